// Round 1
// baseline (115.750 us; speedup 1.0000x reference)
//
#include <hip/hip_runtime.h>

#define EPS 1e-5f

// One thread per (b, n, k) neighbor point.
// enc = [rel.x, rel.y, rel.z, |rel|]; h = relu(BN1(enc @ W1^T)); out = relu(BN2(h @ W2^T)).
// BN folded as: y[o] = relu(fma(dot(W[o], x), scale[o], shift[o])),
// scale = g*rsqrt(v+eps), shift = b - m*scale. W stays raw (uniform s_loads -> SGPRs).
__global__ __launch_bounds__(256) void lse_kernel(
    const float* __restrict__ coords,   // (B,N,3)
    const float* __restrict__ nbr,      // (B,N,K,3)
    const float* __restrict__ W1,       // (4,4) row-major (o,c)
    const float* __restrict__ g1, const float* __restrict__ b1,
    const float* __restrict__ m1, const float* __restrict__ v1,
    const float* __restrict__ W2,       // (8,4) row-major (o,c)
    const float* __restrict__ g2, const float* __restrict__ b2,
    const float* __restrict__ m2, const float* __restrict__ v2,
    float* __restrict__ out,            // (B,N,K,8)
    int total)                          // B*N*K
{
    int tid = blockIdx.x * blockDim.x + threadIdx.x;
    if (tid >= total) return;

    // ---- BN affine params (wave-uniform; cheap) ----
    float sc1[4], sh1[4];
#pragma unroll
    for (int o = 0; o < 4; ++o) {
        float s = g1[o] * rsqrtf(v1[o] + EPS);
        sc1[o] = s;
        sh1[o] = b1[o] - m1[o] * s;
    }
    float sc2[8], sh2[8];
#pragma unroll
    for (int o = 0; o < 8; ++o) {
        float s = g2[o] * rsqrtf(v2[o] + EPS);
        sc2[o] = s;
        sh2[o] = b2[o] - m2[o] * s;
    }

    // ---- encoding ----
    int bn = tid >> 4;  // K = 16
    float cx = coords[bn * 3 + 0];
    float cy = coords[bn * 3 + 1];
    float cz = coords[bn * 3 + 2];
    float nx = nbr[(size_t)tid * 3 + 0];
    float ny = nbr[(size_t)tid * 3 + 1];
    float nz = nbr[(size_t)tid * 3 + 2];
    float rx = nx - cx, ry = ny - cy, rz = nz - cz;
    float dist = sqrtf(rx * rx + ry * ry + rz * rz);
    float enc[4] = {rx, ry, rz, dist};

    // ---- layer 1: 4 -> 4, BN + ReLU ----
    float h[4];
#pragma unroll
    for (int o = 0; o < 4; ++o) {
        float a = 0.f;
#pragma unroll
        for (int c = 0; c < 4; ++c) a += W1[o * 4 + c] * enc[c];
        h[o] = fmaxf(fmaf(a, sc1[o], sh1[o]), 0.f);
    }

    // ---- layer 2: 4 -> 8, BN + ReLU ----
    float r[8];
#pragma unroll
    for (int o = 0; o < 8; ++o) {
        float a = 0.f;
#pragma unroll
        for (int c = 0; c < 4; ++c) a += W2[o * 4 + c] * h[c];
        r[o] = fmaxf(fmaf(a, sc2[o], sh2[o]), 0.f);
    }

    // ---- store: 32 B per thread as two float4 (dense across wave) ----
    float4* op = (float4*)(out + (size_t)tid * 8);
    op[0] = make_float4(r[0], r[1], r[2], r[3]);
    op[1] = make_float4(r[4], r[5], r[6], r[7]);
}

extern "C" void kernel_launch(void* const* d_in, const int* in_sizes, int n_in,
                              void* d_out, int out_size, void* d_ws, size_t ws_size,
                              hipStream_t stream) {
    const float* coords = (const float*)d_in[0];
    const float* nbr    = (const float*)d_in[1];
    const float* W1     = (const float*)d_in[2];
    const float* g1     = (const float*)d_in[3];
    const float* b1     = (const float*)d_in[4];
    const float* m1     = (const float*)d_in[5];
    const float* v1     = (const float*)d_in[6];
    const float* W2     = (const float*)d_in[7];
    const float* g2     = (const float*)d_in[8];
    const float* b2     = (const float*)d_in[9];
    const float* m2     = (const float*)d_in[10];
    const float* v2     = (const float*)d_in[11];
    float* out = (float*)d_out;

    int total = in_sizes[1] / 3;  // B*N*K
    int block = 256;
    int grid = (total + block - 1) / block;
    lse_kernel<<<grid, block, 0, stream>>>(coords, nbr, W1, g1, b1, m1, v1,
                                           W2, g2, b2, m2, v2, out, total);
}